// Round 1
// baseline (519.815 us; speedup 1.0000x reference)
//
#include <hip/hip_runtime.h>
#include <math.h>

// ProGAT: B=8,S=512,NB=23,INIT=512,E=256,R=3,T=2
// Key hoists: gather commutes with row-wise linear+activation, so all
// neighbor matmuls are computed on the 4096 base rows and gathered after.
// Sequence loop (T=2) has invariant score/ctx -> compute seq_ctx once.

#define BSZ   8
#define SEQ   512
#define NBR   23
#define EMB   256
#define INITD 512
#define BS    (BSZ*SEQ)     // 4096
#define G3    (3*EMB)       // 768
#define NEGV  -9e8f

__device__ __forceinline__ float lrelu(float x){ return x > 0.f ? x : 0.01f*x; }
__device__ __forceinline__ float elu1 (float x){ return x > 0.f ? x : (expf(x)-1.f); }
__device__ __forceinline__ float sigm (float x){ return 1.f/(1.f+expf(-x)); }

// C[M][N] = act(A[M][K] @ W[N][K]^T + bias[N]); tiles 64x64x16, 4x4/thread.
template<int ACT>  // 0 = none, 1 = leaky_relu(0.01)
__global__ __launch_bounds__(256) void gemm_bias_act(
    const float* __restrict__ A, const float* __restrict__ W,
    const float* __restrict__ bias, float* __restrict__ C,
    int M, int N, int K)
{
    __shared__ __align__(16) float As[16][64];
    __shared__ __align__(16) float Ws[16][64];
    const int tid = threadIdx.x;
    const int m0 = blockIdx.x * 64;
    const int n0 = blockIdx.y * 64;
    const int tm = tid & 15, tn = tid >> 4;
    const int lr = tid >> 2;          // 0..63
    const int lk = (tid & 3) << 2;    // 0,4,8,12
    float c[4][4] = {};
    for (int k0 = 0; k0 < K; k0 += 16) {
        float4 av = *reinterpret_cast<const float4*>(&A[(size_t)(m0+lr)*K + k0 + lk]);
        float4 wv = *reinterpret_cast<const float4*>(&W[(size_t)(n0+lr)*K + k0 + lk]);
        As[lk+0][lr]=av.x; As[lk+1][lr]=av.y; As[lk+2][lr]=av.z; As[lk+3][lr]=av.w;
        Ws[lk+0][lr]=wv.x; Ws[lk+1][lr]=wv.y; Ws[lk+2][lr]=wv.z; Ws[lk+3][lr]=wv.w;
        __syncthreads();
        #pragma unroll
        for (int k = 0; k < 16; ++k) {
            float4 a = *reinterpret_cast<const float4*>(&As[k][tm<<2]);
            float4 b = *reinterpret_cast<const float4*>(&Ws[k][tn<<2]);
            float avr[4] = {a.x,a.y,a.z,a.w};
            float bvr[4] = {b.x,b.y,b.z,b.w};
            #pragma unroll
            for (int i=0;i<4;++i)
                #pragma unroll
                for (int j=0;j<4;++j) c[i][j] += avr[i]*bvr[j];
        }
        __syncthreads();
    }
    #pragma unroll
    for (int i=0;i<4;++i) {
        int m = m0 + (tm<<2) + i;
        float vv[4];
        #pragma unroll
        for (int j=0;j<4;++j) {
            float t = c[i][j] + bias[n0 + (tn<<2) + j];
            if (ACT == 1) t = lrelu(t);
            vv[j] = t;
        }
        *reinterpret_cast<float4*>(&C[(size_t)m*N + n0 + (tn<<2)]) =
            make_float4(vv[0],vv[1],vv[2],vv[3]);
    }
}

// cdot[r] = Xc[r]·aW[0:E], ndot[r] = Xn[r]·aW[E:2E]; one wave per row.
__global__ __launch_bounds__(256) void dot2_kernel(
    const float* __restrict__ Xc, const float* __restrict__ Xn,
    const float* __restrict__ aW,
    float* __restrict__ cdot, float* __restrict__ ndot)
{
    const int lane = threadIdx.x & 63;
    const int wv   = threadIdx.x >> 6;
    const int r    = blockIdx.x * 4 + wv;
    const int e    = lane << 2;
    float4 xc = *reinterpret_cast<const float4*>(&Xc[(size_t)r*EMB + e]);
    float4 xn = *reinterpret_cast<const float4*>(&Xn[(size_t)r*EMB + e]);
    float4 w0 = *reinterpret_cast<const float4*>(&aW[e]);
    float4 w1 = *reinterpret_cast<const float4*>(&aW[EMB + e]);
    float ac = xc.x*w0.x + xc.y*w0.y + xc.z*w0.z + xc.w*w0.w;
    float an = xn.x*w1.x + xn.y*w1.y + xn.z*w1.z + xn.w*w1.w;
    #pragma unroll
    for (int off = 32; off; off >>= 1) {
        ac += __shfl_xor(ac, off, 64);
        an += __shfl_xor(an, off, 64);
    }
    if (lane == 0) { cdot[r] = ac; ndot[r] = an; }
}

// Per row r: neighbor softmax over NB, ctx[r] = elu(sum_n w_n * nt[gathered n]).
__global__ __launch_bounds__(256) void attn_kernel(
    const float* __restrict__ cdot, const float* __restrict__ ndot,
    const int* __restrict__ idx, const float* __restrict__ nt,
    const float* __restrict__ alignB, float* __restrict__ ctx)
{
    const int r   = blockIdx.x;
    const int b   = r >> 9;       // /SEQ
    const int tid = threadIdx.x;
    __shared__ float w_s[NBR];
    __shared__ float vm_s[NBR];
    __shared__ int   row_s[NBR];
    __shared__ float red[2];
    if (tid < NBR) {
        int j = idx[(size_t)r*NBR + tid];
        int valid = (j >= 0);
        int jj = valid ? j : j + SEQ;       // JAX wrap: f[-1] = last row
        int row = b*SEQ + jj;
        row_s[tid] = row;
        vm_s[tid]  = (float)valid;
        float sc = lrelu(cdot[r] + ndot[row] + alignB[0]);
        w_s[tid] = sc + (valid ? 0.f : NEGV);
    }
    __syncthreads();
    if (tid == 0) {
        float m = w_s[0];
        for (int n = 1; n < NBR; ++n) m = fmaxf(m, w_s[n]);
        red[0] = m;
    }
    __syncthreads();
    if (tid < NBR) w_s[tid] = expf(w_s[tid] - red[0]);
    __syncthreads();
    if (tid == 0) {
        float s = 0.f;
        for (int n = 0; n < NBR; ++n) s += w_s[n];
        red[1] = 1.f / s;
    }
    __syncthreads();
    if (tid < NBR) w_s[tid] *= red[1] * vm_s[tid];
    __syncthreads();
    float acc = 0.f;
    #pragma unroll 1
    for (int n = 0; n < NBR; ++n)
        acc += w_s[n] * nt[(size_t)row_s[n]*EMB + tid];
    ctx[(size_t)r*EMB + tid] = elu1(acc);
}

// h' = GRU(gi, gh, hprev); act = relu(h')
__global__ __launch_bounds__(256) void gru_kernel(
    const float* __restrict__ gi, const float* __restrict__ gh,
    const float* __restrict__ hprev,
    float* __restrict__ hout, float* __restrict__ actout)
{
    const size_t r = blockIdx.x;
    const int    e = threadIdx.x;
    float ir = gi[r*G3 + e], iz = gi[r*G3 + EMB + e], in_ = gi[r*G3 + 2*EMB + e];
    float hr = gh[r*G3 + e], hz = gh[r*G3 + EMB + e], hn  = gh[r*G3 + 2*EMB + e];
    float rg = sigm(ir + hr);
    float z  = sigm(iz + hz);
    float n  = tanhf(in_ + rg*hn);
    float hp = hprev[r*EMB + e];
    float hv = (1.f - z)*n + z*hp;
    hout[r*EMB + e]   = hv;
    actout[r*EMB + e] = fmaxf(hv, 0.f);
}

// seq_feature[b] = sum_s act[b,s]*mask[b,s]; cmol[b] = relu(seq_feature[b])·saW[0:E]
__global__ __launch_bounds__(256) void seqsum_kernel(
    const float* __restrict__ act, const float* __restrict__ mask,
    const float* __restrict__ saW,
    float* __restrict__ seqfeat, float* __restrict__ cmol)
{
    const int b = blockIdx.x;
    const int e = threadIdx.x;
    float acc = 0.f;
    for (int s = 0; s < SEQ; ++s)
        acc += act[((size_t)b*SEQ + s)*EMB + e] * mask[b*SEQ + s];
    seqfeat[b*EMB + e] = acc;
    __shared__ float red[256];
    red[e] = fmaxf(acc, 0.f) * saW[e];
    __syncthreads();
    for (int off = 128; off; off >>= 1) {
        if (e < off) red[e] += red[e + off];
        __syncthreads();
    }
    if (e == 0) cmol[b] = red[0];
}

// Sequence attention: softmax over S, seq_ctx[b] = elu(sum_s w_s * tf[b,s,:])
__global__ __launch_bounds__(512) void seqattn_kernel(
    const float* __restrict__ act, const float* __restrict__ mask,
    const float* __restrict__ saW, const float* __restrict__ saB,
    const float* __restrict__ cmol, const float* __restrict__ tf,
    float* __restrict__ seqctx)
{
    const int b   = blockIdx.x;
    const int tid = threadIdx.x;   // one s per thread
    __shared__ float w_s[SEQ];
    __shared__ float red[SEQ];
    const float* arow = &act[((size_t)b*SEQ + tid)*EMB];
    const float* w2 = &saW[EMB];
    float ad = 0.f;
    for (int e = 0; e < EMB; e += 4) {
        float4 a = *reinterpret_cast<const float4*>(&arow[e]);
        float4 w = *reinterpret_cast<const float4*>(&w2[e]);
        ad += a.x*w.x + a.y*w.y + a.z*w.z + a.w*w.w;
    }
    float mk = mask[b*SEQ + tid];
    float sc = lrelu(cmol[b] + ad + saB[0]) + (mk == 0.f ? NEGV : 0.f);
    red[tid] = sc; __syncthreads();
    for (int off = 256; off; off >>= 1) {
        if (tid < off) red[tid] = fmaxf(red[tid], red[tid + off]);
        __syncthreads();
    }
    float m = red[0]; __syncthreads();
    float ev = expf(sc - m);
    red[tid] = ev; __syncthreads();
    for (int off = 256; off; off >>= 1) {
        if (tid < off) red[tid] += red[tid + off];
        __syncthreads();
    }
    float inv = 1.f / red[0];
    w_s[tid] = ev * inv * mk;
    __syncthreads();
    if (tid < EMB) {
        float acc = 0.f;
        for (int s = 0; s < SEQ; ++s)
            acc += w_s[s] * tf[((size_t)b*SEQ + s)*EMB + tid];
        seqctx[b*EMB + tid] = elu1(acc);
    }
}

// Tiny per-batch GRU step (8 rows); also writes act_seq = relu(h').
__global__ __launch_bounds__(256) void seqgru_kernel(
    const float* __restrict__ seqctx, const float* __restrict__ sfin,
    const float* __restrict__ wih, const float* __restrict__ bih,
    const float* __restrict__ whh, const float* __restrict__ bhh,
    float* __restrict__ sfout, float* __restrict__ actseq)
{
    const int b = blockIdx.x;
    const int tid = threadIdx.x;
    __shared__ float xs[EMB], hs[EMB], gis[G3], ghs[G3];
    xs[tid] = seqctx[b*EMB + tid];
    hs[tid] = sfin[b*EMB + tid];
    __syncthreads();
    for (int g = tid; g < G3; g += 256) {
        const float* wi = &wih[(size_t)g*EMB];
        const float* wh = &whh[(size_t)g*EMB];
        float a = bih[g], c = bhh[g];
        for (int e = 0; e < EMB; ++e) { a += xs[e]*wi[e]; c += hs[e]*wh[e]; }
        gis[g] = a; ghs[g] = c;
    }
    __syncthreads();
    float rg = sigm(gis[tid] + ghs[tid]);
    float z  = sigm(gis[EMB + tid] + ghs[EMB + tid]);
    float n  = tanhf(gis[2*EMB + tid] + rg*ghs[2*EMB + tid]);
    float hv = (1.f - z)*n + z*hs[tid];
    sfout[b*EMB + tid]  = hv;
    actseq[b*EMB + tid] = fmaxf(hv, 0.f);
}

extern "C" void kernel_launch(void* const* d_in, const int* in_sizes, int n_in,
                              void* d_out, int out_size, void* d_ws, size_t ws_size,
                              hipStream_t stream) {
    (void)in_sizes; (void)n_in; (void)out_size; (void)ws_size;
    const float* amino  = (const float*)d_in[0];
    const float* mask   = (const float*)d_in[1];
    const float* embW   = (const float*)d_in[2];
    const float* embB   = (const float*)d_in[3];
    const float* nbW    = (const float*)d_in[4];
    const float* nbB    = (const float*)d_in[5];
    const float* alignW = (const float*)d_in[6];
    const float* alignB = (const float*)d_in[7];
    const float* attW   = (const float*)d_in[8];
    const float* attB   = (const float*)d_in[9];
    const float* gwih   = (const float*)d_in[10];
    const float* gwhh   = (const float*)d_in[11];
    const float* gbih   = (const float*)d_in[12];
    const float* gbhh   = (const float*)d_in[13];
    const float* saW    = (const float*)d_in[14];
    const float* saB    = (const float*)d_in[15];
    const float* satW   = (const float*)d_in[16];
    const float* satB   = (const float*)d_in[17];
    const float* sgwih  = (const float*)d_in[18];  // dict order: wih, bih, whh, bhh
    const float* sgbih  = (const float*)d_in[19];
    const float* sgwhh  = (const float*)d_in[20];
    const float* sgbhh  = (const float*)d_in[21];
    const int*   idx    = (const int*)d_in[22];

    float* ws = (float*)d_ws;
    size_t o = 0;
    float* feat   = ws + o; o += (size_t)BS*EMB;
    float* nbase  = ws + o; o += (size_t)BS*EMB;
    float* nt     = ws + o; o += (size_t)BS*EMB;   // reused as tf in seq phase
    float* ctxb   = ws + o; o += (size_t)BS*EMB;
    float* h      = ws + o; o += (size_t)BS*EMB;
    float* gi     = ws + o; o += (size_t)BS*G3;
    float* gh     = ws + o; o += (size_t)BS*G3;
    float* cdot   = ws + o; o += BS;
    float* ndot   = ws + o; o += BS;
    float* seqfeat= ws + o; o += BSZ*EMB;
    float* cmol   = ws + o; o += BSZ;
    float* seqctx = ws + o; o += BSZ*EMB;

    float* out    = (float*)d_out;
    float* actseq = out;             // (B,E)
    float* act    = out + BSZ*EMB;   // (B,S,E) final act lives in d_out

    // feat/nbase from amino (K=512)
    gemm_bias_act<1><<<dim3(BS/64, EMB/64), 256, 0, stream>>>(amino, embW, embB, feat, BS, EMB, INITD);
    gemm_bias_act<1><<<dim3(BS/64, EMB/64), 256, 0, stream>>>(amino, nbW,  nbB,  nbase, BS, EMB, INITD);

    for (int d = 0; d < 3; ++d) {
        const float* center  = (d == 0) ? feat  : act;
        const float* nbrbase = (d == 0) ? nbase : act;
        const float* hprev   = (d == 0) ? feat  : h;
        gemm_bias_act<0><<<dim3(BS/64, EMB/64), 256, 0, stream>>>(
            nbrbase, attW + (size_t)d*EMB*EMB, attB + d*EMB, nt, BS, EMB, EMB);
        dot2_kernel<<<BS/4, 256, 0, stream>>>(center, nbrbase, alignW + d*2*EMB, cdot, ndot);
        attn_kernel<<<BS, 256, 0, stream>>>(cdot, ndot, idx, nt, alignB + d, ctxb);
        gemm_bias_act<0><<<dim3(BS/64, G3/64), 256, 0, stream>>>(
            ctxb, gwih + (size_t)d*G3*EMB, gbih + d*G3, gi, BS, G3, EMB);
        gemm_bias_act<0><<<dim3(BS/64, G3/64), 256, 0, stream>>>(
            hprev, gwhh + (size_t)d*G3*EMB, gbhh + d*G3, gh, BS, G3, EMB);
        gru_kernel<<<BS, 256, 0, stream>>>(gi, gh, hprev, h, act);
    }

    // sequence phase (scores/ctx invariant across T=2 -> compute once)
    seqsum_kernel<<<BSZ, 256, 0, stream>>>(act, mask, saW, seqfeat, cmol);
    gemm_bias_act<0><<<dim3(BS/64, EMB/64), 256, 0, stream>>>(act, satW, satB, nt, BS, EMB, EMB);
    seqattn_kernel<<<BSZ, 512, 0, stream>>>(act, mask, saW, saB, cmol, nt, seqctx);
    seqgru_kernel<<<BSZ, 256, 0, stream>>>(seqctx, seqfeat, sgwih, sgbih, sgwhh, sgbhh, seqfeat, actseq);
    seqgru_kernel<<<BSZ, 256, 0, stream>>>(seqctx, seqfeat, sgwih, sgbih, sgwhh, sgbhh, seqfeat, actseq);
}

// Round 2
// 241.490 us; speedup vs baseline: 2.1525x; 2.1525x over previous
//
#include <hip/hip_runtime.h>
#include <math.h>

// ProGAT: B=8,S=512,NB=23,INIT=512,E=256,R=3,T=2
// R2: bf16 MFMA GEMMs (16x16x32, 64x64 tile, XOR-swizzled LDS), parallel seq-GRU.

#define BSZ   8
#define SEQ   512
#define NBR   23
#define EMB   256
#define INITD 512
#define BS    (BSZ*SEQ)     // 4096
#define G3    (3*EMB)       // 768
#define NEGV  -9e8f

typedef __attribute__((ext_vector_type(8))) short short8;
typedef __attribute__((ext_vector_type(4))) float f32x4;

__device__ __forceinline__ float lrelu(float x){ return x > 0.f ? x : 0.01f*x; }
__device__ __forceinline__ float elu1 (float x){ return x > 0.f ? x : (expf(x)-1.f); }
__device__ __forceinline__ float sigm (float x){ return 1.f/(1.f+expf(-x)); }
__device__ __forceinline__ float bf2f(ushort u){
    union { unsigned int i; float f; } v; v.i = ((unsigned int)u) << 16; return v.f;
}
__device__ __forceinline__ ushort f2bf(float f){
    union { float f; unsigned int i; } v; v.f = f;
    unsigned int u = v.i;
    return (ushort)((u + 0x7FFFu + ((u >> 16) & 1u)) >> 16);   // RNE
}

// ---- fp32 -> bf16 converter, 7 segments in one dispatch (blockIdx.y = seg)
__global__ __launch_bounds__(256) void convert7_kernel(
    const float* s0, ushort* d0, int n0,
    const float* s1, ushort* d1, int n1,
    const float* s2, ushort* d2, int n2,
    const float* s3, ushort* d3, int n3,
    const float* s4, ushort* d4, int n4,
    const float* s5, ushort* d5, int n5,
    const float* s6, ushort* d6, int n6)
{
    const float* srcs[7] = {s0,s1,s2,s3,s4,s5,s6};
    ushort* dsts[7] = {d0,d1,d2,d3,d4,d5,d6};
    int ns[7] = {n0,n1,n2,n3,n4,n5,n6};
    int seg = blockIdx.y;
    const float* s = srcs[seg]; ushort* d = dsts[seg]; int n = ns[seg];
    size_t i = ((size_t)blockIdx.x * 256 + threadIdx.x) * 8;
    size_t stride = (size_t)gridDim.x * 256 * 8;
    for (; i < (size_t)n; i += stride) {
        float4 a = *reinterpret_cast<const float4*>(s + i);
        float4 b = *reinterpret_cast<const float4*>(s + i + 4);
        uint4 o;
        o.x = (unsigned)f2bf(a.x) | ((unsigned)f2bf(a.y) << 16);
        o.y = (unsigned)f2bf(a.z) | ((unsigned)f2bf(a.w) << 16);
        o.z = (unsigned)f2bf(b.x) | ((unsigned)f2bf(b.y) << 16);
        o.w = (unsigned)f2bf(b.z) | ((unsigned)f2bf(b.w) << 16);
        *reinterpret_cast<uint4*>(d + i) = o;
    }
}

// ---- C[M][N] = act(Abf[M][K] @ Wbf[N][K]^T + bias[N]); MFMA 16x16x32 bf16.
// 64x64 tile, 4 waves (wave w -> rows 16w..16w+15 x all 64 cols), BK=64.
// LDS XOR-swizzle (T2): chunk' = c8 ^ (row&7) kills the stride-128B bank conflict.
template<int ACT, bool WF32, bool WBF>
__global__ __launch_bounds__(256) void gemm_mfma(
    const ushort* __restrict__ A, const ushort* __restrict__ W,
    const float* __restrict__ bias,
    float* __restrict__ C, ushort* __restrict__ Cbf,
    int M, int N, int K)
{
    __shared__ __align__(16) ushort As[64][64];
    __shared__ __align__(16) ushort Ws[64][64];
    const int tid = threadIdx.x;
    const int m0 = blockIdx.x * 64, n0 = blockIdx.y * 64;
    const int wv = tid >> 6, lane = tid & 63;
    const int fr = lane & 15, grp = lane >> 4;
    const int lrow = tid >> 3, lc8 = tid & 7;   // staging: 8 lanes per row, 128B/row
    const int kc = K >> 3;                       // row stride in 16B chunks

    f32x4 acc[4];
    #pragma unroll
    for (int c = 0; c < 4; ++c) acc[c] = (f32x4){0.f, 0.f, 0.f, 0.f};

    const float4* A4 = reinterpret_cast<const float4*>(A);
    const float4* W4 = reinterpret_cast<const float4*>(W);
    const int sw = lc8 ^ (lrow & 7);             // (lrow+32)&7 == lrow&7

    for (int k0 = 0; k0 < K; k0 += 64) {
        float4 a0 = A4[(size_t)(m0 + lrow)      * kc + (k0 >> 3) + lc8];
        float4 a1 = A4[(size_t)(m0 + lrow + 32) * kc + (k0 >> 3) + lc8];
        float4 w0 = W4[(size_t)(n0 + lrow)      * kc + (k0 >> 3) + lc8];
        float4 w1 = W4[(size_t)(n0 + lrow + 32) * kc + (k0 >> 3) + lc8];
        if (k0) __syncthreads();
        *reinterpret_cast<float4*>(&As[lrow     ][sw << 3]) = a0;
        *reinterpret_cast<float4*>(&As[lrow + 32][sw << 3]) = a1;
        *reinterpret_cast<float4*>(&Ws[lrow     ][sw << 3]) = w0;
        *reinterpret_cast<float4*>(&Ws[lrow + 32][sw << 3]) = w1;
        __syncthreads();
        #pragma unroll
        for (int ks = 0; ks < 2; ++ks) {
            const int ar = (wv << 4) + fr;
            short8 af = *reinterpret_cast<const short8*>(
                &As[ar][((((ks << 2) + grp) ^ (ar & 7)) << 3)]);
            #pragma unroll
            for (int c = 0; c < 4; ++c) {
                const int br = (c << 4) + fr;
                short8 bfv = *reinterpret_cast<const short8*>(
                    &Ws[br][((((ks << 2) + grp) ^ (br & 7)) << 3)]);
                acc[c] = __builtin_amdgcn_mfma_f32_16x16x32_bf16(af, bfv, acc[c], 0, 0, 0);
            }
        }
    }

    // D layout (m89-verified): col = lane&15, row = (lane>>4)*4 + j
    const int mrow = m0 + (wv << 4) + (grp << 2);
    #pragma unroll
    for (int c = 0; c < 4; ++c) {
        const int n = n0 + (c << 4) + fr;
        const float bv = bias[n];
        #pragma unroll
        for (int j = 0; j < 4; ++j) {
            float t = acc[c][j] + bv;
            if (ACT == 1) t = lrelu(t);
            size_t off = (size_t)(mrow + j) * N + n;
            if (WF32) C[off] = t;
            if (WBF)  Cbf[off] = f2bf(t);
        }
    }
}

// cdot[r] = Xc[r]·aW[0:E], ndot[r] = Xn[r]·aW[E:2E]; one wave per row.
__global__ __launch_bounds__(256) void dot2_kernel(
    const float* __restrict__ Xc, const float* __restrict__ Xn,
    const float* __restrict__ aW,
    float* __restrict__ cdot, float* __restrict__ ndot)
{
    const int lane = threadIdx.x & 63;
    const int wv   = threadIdx.x >> 6;
    const int r    = blockIdx.x * 4 + wv;
    const int e    = lane << 2;
    float4 xc = *reinterpret_cast<const float4*>(&Xc[(size_t)r*EMB + e]);
    float4 xn = *reinterpret_cast<const float4*>(&Xn[(size_t)r*EMB + e]);
    float4 w0 = *reinterpret_cast<const float4*>(&aW[e]);
    float4 w1 = *reinterpret_cast<const float4*>(&aW[EMB + e]);
    float ac = xc.x*w0.x + xc.y*w0.y + xc.z*w0.z + xc.w*w0.w;
    float an = xn.x*w1.x + xn.y*w1.y + xn.z*w1.z + xn.w*w1.w;
    #pragma unroll
    for (int off = 32; off; off >>= 1) {
        ac += __shfl_xor(ac, off, 64);
        an += __shfl_xor(an, off, 64);
    }
    if (lane == 0) { cdot[r] = ac; ndot[r] = an; }
}

// Per row r: neighbor softmax over NB, ctxbf[r] = bf16(elu(sum_n w_n * nt[row_n])).
__global__ __launch_bounds__(256) void attn_kernel(
    const float* __restrict__ cdot, const float* __restrict__ ndot,
    const int* __restrict__ idx, const ushort* __restrict__ nt,
    const float* __restrict__ alignB, ushort* __restrict__ ctxbf)
{
    const int r   = blockIdx.x;
    const int b   = r >> 9;
    const int tid = threadIdx.x;
    __shared__ float w_s[NBR];
    __shared__ float vm_s[NBR];
    __shared__ int   row_s[NBR];
    __shared__ float red[2];
    if (tid < NBR) {
        int j = idx[(size_t)r*NBR + tid];
        int valid = (j >= 0);
        int jj = valid ? j : j + SEQ;       // JAX wrap: f[-1] = last row
        int row = b*SEQ + jj;
        row_s[tid] = row;
        vm_s[tid]  = (float)valid;
        float sc = lrelu(cdot[r] + ndot[row] + alignB[0]);
        w_s[tid] = sc + (valid ? 0.f : NEGV);
    }
    __syncthreads();
    if (tid == 0) {
        float m = w_s[0];
        for (int n = 1; n < NBR; ++n) m = fmaxf(m, w_s[n]);
        red[0] = m;
    }
    __syncthreads();
    if (tid < NBR) w_s[tid] = expf(w_s[tid] - red[0]);
    __syncthreads();
    if (tid == 0) {
        float s = 0.f;
        for (int n = 0; n < NBR; ++n) s += w_s[n];
        red[1] = 1.f / s;
    }
    __syncthreads();
    if (tid < NBR) w_s[tid] *= red[1] * vm_s[tid];
    __syncthreads();
    float acc = 0.f;
    #pragma unroll 1
    for (int n = 0; n < NBR; ++n)
        acc += w_s[n] * bf2f(nt[(size_t)row_s[n]*EMB + tid]);
    ctxbf[(size_t)r*EMB + tid] = f2bf(elu1(acc));
}

// h' = GRU(gi, gh, hprev); writes h (f32+bf16) and act=relu(h') (f32 + bf16)
__global__ __launch_bounds__(256) void gru_kernel(
    const float* __restrict__ gi, const float* __restrict__ gh,
    const float* __restrict__ hprev,
    float* __restrict__ hout, ushort* __restrict__ hbf,
    float* __restrict__ actout, ushort* __restrict__ actbf)
{
    const size_t r = blockIdx.x;
    const int    e = threadIdx.x;
    float ir = gi[r*G3 + e], iz = gi[r*G3 + EMB + e], in_ = gi[r*G3 + 2*EMB + e];
    float hr = gh[r*G3 + e], hz = gh[r*G3 + EMB + e], hn  = gh[r*G3 + 2*EMB + e];
    float rg = sigm(ir + hr);
    float z  = sigm(iz + hz);
    float n  = tanhf(in_ + rg*hn);
    float hp = hprev[r*EMB + e];
    float hv = (1.f - z)*n + z*hp;
    float av = fmaxf(hv, 0.f);
    hout[r*EMB + e]   = hv;
    hbf[r*EMB + e]    = f2bf(hv);
    actout[r*EMB + e] = av;
    actbf[r*EMB + e]  = f2bf(av);
}

// seq_feature[b] = sum_s act[b,s]*mask[b,s]; cmol[b] = relu(seq_feature[b])·saW[0:E]
__global__ __launch_bounds__(256) void seqsum_kernel(
    const float* __restrict__ act, const float* __restrict__ mask,
    const float* __restrict__ saW,
    float* __restrict__ seqfeat, float* __restrict__ cmol)
{
    const int b = blockIdx.x;
    const int e = threadIdx.x;
    float acc = 0.f;
    for (int s = 0; s < SEQ; ++s)
        acc += act[((size_t)b*SEQ + s)*EMB + e] * mask[b*SEQ + s];
    seqfeat[b*EMB + e] = acc;
    __shared__ float red[256];
    red[e] = fmaxf(acc, 0.f) * saW[e];
    __syncthreads();
    for (int off = 128; off; off >>= 1) {
        if (e < off) red[e] += red[e + off];
        __syncthreads();
    }
    if (e == 0) cmol[b] = red[0];
}

// Sequence attention: softmax over S, seq_ctx[b] = elu(sum_s w_s * tf[b,s,:])
__global__ __launch_bounds__(512) void seqattn_kernel(
    const float* __restrict__ act, const float* __restrict__ mask,
    const float* __restrict__ saW, const float* __restrict__ saB,
    const float* __restrict__ cmol, const float* __restrict__ tf,
    float* __restrict__ seqctx)
{
    const int b   = blockIdx.x;
    const int tid = threadIdx.x;
    __shared__ float w_s[SEQ];
    __shared__ float red[SEQ];
    const float* arow = &act[((size_t)b*SEQ + tid)*EMB];
    const float* w2 = &saW[EMB];
    float ad = 0.f;
    for (int e = 0; e < EMB; e += 4) {
        float4 a = *reinterpret_cast<const float4*>(&arow[e]);
        float4 w = *reinterpret_cast<const float4*>(&w2[e]);
        ad += a.x*w.x + a.y*w.y + a.z*w.z + a.w*w.w;
    }
    float mk = mask[b*SEQ + tid];
    float sc = lrelu(cmol[b] + ad + saB[0]) + (mk == 0.f ? NEGV : 0.f);
    red[tid] = sc; __syncthreads();
    for (int off = 256; off; off >>= 1) {
        if (tid < off) red[tid] = fmaxf(red[tid], red[tid + off]);
        __syncthreads();
    }
    float m = red[0]; __syncthreads();
    float ev = expf(sc - m);
    red[tid] = ev; __syncthreads();
    for (int off = 256; off; off >>= 1) {
        if (tid < off) red[tid] += red[tid + off];
        __syncthreads();
    }
    float inv = 1.f / red[0];
    w_s[tid] = ev * inv * mk;
    __syncthreads();
    if (tid < EMB) {
        float acc = 0.f;
        for (int s = 0; s < SEQ; ++s)
            acc += w_s[s] * tf[((size_t)b*SEQ + s)*EMB + tid];
        seqctx[b*EMB + tid] = elu1(acc);
    }
}

// Y[b][g] = X[b]·Wm[g] + bias[g];  one wave per (b,g). grid (192, 8).
__global__ __launch_bounds__(256) void matvec8_kernel(
    const float* __restrict__ X, const float* __restrict__ Wm,
    const float* __restrict__ bias, float* __restrict__ Y)
{
    const int g    = blockIdx.x * 4 + (threadIdx.x >> 6);
    const int b    = blockIdx.y;
    const int lane = threadIdx.x & 63;
    float4 w = *reinterpret_cast<const float4*>(&Wm[(size_t)g*EMB + (lane << 2)]);
    float4 x = *reinterpret_cast<const float4*>(&X[(size_t)b*EMB + (lane << 2)]);
    float d = w.x*x.x + w.y*x.y + w.z*x.z + w.w*x.w;
    #pragma unroll
    for (int off = 32; off; off >>= 1) d += __shfl_xor(d, off, 64);
    if (lane == 0) Y[(size_t)b*G3 + g] = d + bias[g];
}

// elementwise GRU combine for seq phase; sfin may alias sfout (1 thread per elem)
__global__ __launch_bounds__(256) void seqgru_el_kernel(
    const float* __restrict__ sgi, const float* __restrict__ sgh,
    const float* __restrict__ sfin,
    float* __restrict__ sfout, float* __restrict__ actseq)
{
    const int b = blockIdx.x;
    const int e = threadIdx.x;
    float rg = sigm(sgi[b*G3 + e]       + sgh[b*G3 + e]);
    float z  = sigm(sgi[b*G3 + EMB + e] + sgh[b*G3 + EMB + e]);
    float n  = tanhf(sgi[b*G3 + 2*EMB + e] + rg * sgh[b*G3 + 2*EMB + e]);
    float hp = sfin[b*EMB + e];
    float hv = (1.f - z)*n + z*hp;
    sfout[b*EMB + e]  = hv;
    actseq[b*EMB + e] = fmaxf(hv, 0.f);
}

extern "C" void kernel_launch(void* const* d_in, const int* in_sizes, int n_in,
                              void* d_out, int out_size, void* d_ws, size_t ws_size,
                              hipStream_t stream) {
    (void)in_sizes; (void)n_in; (void)out_size; (void)ws_size;
    const float* amino  = (const float*)d_in[0];
    const float* mask   = (const float*)d_in[1];
    const float* embW   = (const float*)d_in[2];
    const float* embB   = (const float*)d_in[3];
    const float* nbW    = (const float*)d_in[4];
    const float* nbB    = (const float*)d_in[5];
    const float* alignW = (const float*)d_in[6];
    const float* alignB = (const float*)d_in[7];
    const float* attW   = (const float*)d_in[8];
    const float* attB   = (const float*)d_in[9];
    const float* gwih   = (const float*)d_in[10];
    const float* gwhh   = (const float*)d_in[11];
    const float* gbih   = (const float*)d_in[12];
    const float* gbhh   = (const float*)d_in[13];
    const float* saW    = (const float*)d_in[14];
    const float* saB    = (const float*)d_in[15];
    const float* satW   = (const float*)d_in[16];
    const float* satB   = (const float*)d_in[17];
    const float* sgwih  = (const float*)d_in[18];
    const float* sgbih  = (const float*)d_in[19];
    const float* sgwhh  = (const float*)d_in[20];
    const float* sgbhh  = (const float*)d_in[21];
    const int*   idx    = (const int*)d_in[22];

    char* cur = (char*)d_ws;
    auto alloc = [&](size_t bytes) -> char* {
        char* p = cur; cur += (bytes + 255) & ~(size_t)255; return p;
    };
    float* feat    = (float*)alloc((size_t)BS*EMB*4);
    float* nbase   = (float*)alloc((size_t)BS*EMB*4);
    float* h       = (float*)alloc((size_t)BS*EMB*4);
    float* gi      = (float*)alloc((size_t)BS*G3*4);
    float* gh      = (float*)alloc((size_t)BS*G3*4);
    float* cdot    = (float*)alloc(BS*4);
    float* ndot    = (float*)alloc(BS*4);
    float* seqfeat = (float*)alloc(BSZ*EMB*4);
    float* cmol    = (float*)alloc(64*4);
    float* seqctx  = (float*)alloc(BSZ*EMB*4);
    float* sgi     = (float*)alloc(BSZ*G3*4);
    float* sgh     = (float*)alloc(BSZ*G3*4);
    ushort* featbf  = (ushort*)alloc((size_t)BS*EMB*2);
    ushort* nbasebf = (ushort*)alloc((size_t)BS*EMB*2);
    ushort* actbf   = (ushort*)alloc((size_t)BS*EMB*2);
    ushort* hbf     = (ushort*)alloc((size_t)BS*EMB*2);
    ushort* ctxbf   = (ushort*)alloc((size_t)BS*EMB*2);
    ushort* ntb     = (ushort*)alloc((size_t)BS*EMB*2);
    ushort* embWbf  = (ushort*)alloc((size_t)EMB*INITD*2);
    ushort* nbWbf   = (ushort*)alloc((size_t)EMB*INITD*2);
    ushort* attWbf  = (ushort*)alloc((size_t)3*EMB*EMB*2);
    ushort* gwihbf  = (ushort*)alloc((size_t)3*G3*EMB*2);
    ushort* gwhhbf  = (ushort*)alloc((size_t)3*G3*EMB*2);
    ushort* satWbf  = (ushort*)alloc((size_t)EMB*EMB*2);
    ushort* aminobf = (ushort*)gi;     // alias: gi first written after aminobf dead
    float*  tf      = gi;              // alias: seq phase after GRU rounds

    float* out    = (float*)d_out;
    float* actseq = out;               // (B,E)
    float* act    = out + BSZ*EMB;     // (B,S,E)

    // bf16 conversions (amino + 6 weight arrays) in one dispatch
    convert7_kernel<<<dim3(1024, 7), 256, 0, stream>>>(
        amino, aminobf, BS*INITD,
        embW,  embWbf,  EMB*INITD,
        nbW,   nbWbf,   EMB*INITD,
        attW,  attWbf,  3*EMB*EMB,
        gwih,  gwihbf,  3*G3*EMB,
        gwhh,  gwhhbf,  3*G3*EMB,
        satW,  satWbf,  EMB*EMB);

    gemm_mfma<1,true,true><<<dim3(BS/64, EMB/64), 256, 0, stream>>>(
        aminobf, embWbf, embB, feat, featbf, BS, EMB, INITD);
    gemm_mfma<1,true,true><<<dim3(BS/64, EMB/64), 256, 0, stream>>>(
        aminobf, nbWbf, nbB, nbase, nbasebf, BS, EMB, INITD);

    for (int d = 0; d < 3; ++d) {
        const float*  center   = (d == 0) ? feat    : act;
        const float*  nbrbase  = (d == 0) ? nbase   : act;
        const ushort* nbrbf    = (d == 0) ? nbasebf : actbf;
        const float*  hprev    = (d == 0) ? feat    : h;
        const ushort* hprevbf  = (d == 0) ? featbf  : hbf;
        gemm_mfma<0,false,true><<<dim3(BS/64, EMB/64), 256, 0, stream>>>(
            nbrbf, attWbf + (size_t)d*EMB*EMB, attB + d*EMB, nullptr, ntb, BS, EMB, EMB);
        dot2_kernel<<<BS/4, 256, 0, stream>>>(center, nbrbase, alignW + d*2*EMB, cdot, ndot);
        attn_kernel<<<BS, 256, 0, stream>>>(cdot, ndot, idx, ntb, alignB + d, ctxbf);
        gemm_mfma<0,true,false><<<dim3(BS/64, G3/64), 256, 0, stream>>>(
            ctxbf, gwihbf + (size_t)d*G3*EMB, gbih + d*G3, gi, nullptr, BS, G3, EMB);
        gemm_mfma<0,true,false><<<dim3(BS/64, G3/64), 256, 0, stream>>>(
            hprevbf, gwhhbf + (size_t)d*G3*EMB, gbhh + d*G3, gh, nullptr, BS, G3, EMB);
        gru_kernel<<<BS, 256, 0, stream>>>(gi, gh, hprev, h, hbf, act, actbf);
    }

    // sequence phase (scores/ctx invariant across T=2 -> compute once)
    seqsum_kernel<<<BSZ, 256, 0, stream>>>(act, mask, saW, seqfeat, cmol);
    gemm_mfma<0,true,false><<<dim3(BS/64, EMB/64), 256, 0, stream>>>(
        actbf, satWbf, satB, tf, nullptr, BS, EMB, EMB);
    seqattn_kernel<<<BSZ, 512, 0, stream>>>(act, mask, saW, saB, cmol, tf, seqctx);
    matvec8_kernel<<<dim3(G3/4, BSZ), 256, 0, stream>>>(seqctx, sgwih, sgbih, sgi);
    for (int t = 0; t < 2; ++t) {
        matvec8_kernel<<<dim3(G3/4, BSZ), 256, 0, stream>>>(seqfeat, sgwhh, sgbhh, sgh);
        seqgru_el_kernel<<<BSZ, 256, 0, stream>>>(sgi, sgh, seqfeat, seqfeat, actseq);
    }
}